// Round 11
// baseline (255.697 us; speedup 1.0000x reference)
//
#include <hip/hip_runtime.h>
#include <hip/hip_bf16.h>

#define NN 50000
#define NE 800000
#define FIN 128
#define HC1 256
#define HC2 128
#define EPSV 1e-5f
#define NTILE 196     // ceil(NN/256)
#define CAP 8448      // per-tile bucket/CSR capacity
#define FILLMAX (CAP - 3840)  // 4608: max bucket entries consumed -> scan total <= CAP always

typedef __attribute__((ext_vector_type(8))) short bf8;     // 8 bf16 (4 VGPRs) MFMA operand
typedef __attribute__((ext_vector_type(16))) float f32x16; // 32x32 MFMA accumulator

union BF8U { bf8 v; ushort u[8]; uint4 q; };

__device__ __forceinline__ float bf2f(ushort u) {
    union { uint i; float f; } c; c.i = ((uint)u) << 16; return c.f;
}
__device__ __forceinline__ float ulo(uint u) {
    union { uint i; float f; } c; c.i = u << 16; return c.f;
}
__device__ __forceinline__ float uhi(uint u) {
    union { uint i; float f; } c; c.i = u & 0xffff0000u; return c.f;
}
__device__ __forceinline__ ushort f2bf(float f) {
    return __builtin_bit_cast(ushort, __float2bfloat16(f));  // RNE
}

// ---------------- init: zero bucket cursors + stats + sentinel row ----------------
__global__ void k_init(int* __restrict__ gcur, float* __restrict__ stats, uint* __restrict__ s0row) {
    int i = blockIdx.x * blockDim.x + threadIdx.x;
    if (i < 256) gcur[i] = 0;
    if (i < 1024) stats[i] = 0.0f;
    if (i < 64) s0row[i] = 0u;   // zero sentinel row (index NN) of s0 buffer
}

// ---------------- merged: bucket-fill || colstats<128>(x) || wprep(w1) || wprep(w2) ----------------
#define BKB 784     // fill blocks (1024 edges each, 4 per thread)
#define SB 391      // colstats blocks
#define WB 128      // wprep blocks each

__device__ __forceinline__ void wprep_body(const float* __restrict__ W, ushort* __restrict__ wp,
                                           int idx, int K, int NC) {
    int j = idx & 7;
    int lane = (idx >> 3) & 63;
    int ts = idx >> 9;
    int KS = K / 16;
    int s = ts % KS;
    int t = ts / KS;
    int n = t * 32 + (lane & 31);
    int k = s * 16 + (lane >> 5) * 8 + j;
    wp[idx] = f2bf(W[(size_t)k * NC + n]);
}

__global__ __launch_bounds__(256) void k_bucket(
    const int* __restrict__ ei, int* __restrict__ gcur, uint* __restrict__ buckets,
    const float* __restrict__ x, float* __restrict__ sum, float* __restrict__ sumsq,
    const float* __restrict__ w1, ushort* __restrict__ wp1,
    const float* __restrict__ w2, ushort* __restrict__ wp2) {
    int b = blockIdx.x;
    int t = threadIdx.x;
    if (b < BKB) {
        __shared__ int hist[NTILE];
        __shared__ int base[NTILE];
        if (t < NTILE) hist[t] = 0;
        __syncthreads();
        int e0 = b * 1024;
        int es[4], ed[4];
#pragma unroll
        for (int i = 0; i < 4; ++i) {
            int e = e0 + i * 256 + t;
            if (e < NE) {
                int s = ei[e];
                int d = ei[NE + e];
                s = min(max(s, 0), NN - 1);
                d = min(max(d, 0), NN - 1);
                es[i] = s; ed[i] = d;
                atomicAdd(&hist[d >> 8], 1);
            } else es[i] = -1;
        }
        __syncthreads();
        if (t < NTILE) base[t] = atomicAdd(&gcur[t], hist[t]);
        __syncthreads();
        if (t < NTILE) hist[t] = 0;   // reuse as local cursor
        __syncthreads();
#pragma unroll
        for (int i = 0; i < 4; ++i) {
            if (es[i] >= 0) {
                int tile = ed[i] >> 8;
                int lofs = atomicAdd(&hist[tile], 1);
                int pos = base[tile] + lofs;
                if (pos < CAP) buckets[(size_t)tile * CAP + pos] = ((uint)es[i] << 8) | (uint)(ed[i] & 255);
            }
        }
        return;
    }
    if (b < BKB + SB) {
        const int F4 = 32, RIF = 8, RPB = 128;
        int c4 = t & 31;
        int ro = t >> 5;
        int r0 = (b - BKB) * RPB;
        int r1 = min(r0 + RPB, NN);
        float4 s = make_float4(0.f, 0.f, 0.f, 0.f);
        float4 q = make_float4(0.f, 0.f, 0.f, 0.f);
        for (int r = r0 + ro; r < r1; r += RIF) {
            float4 v = ((const float4*)x)[(size_t)r * F4 + c4];
            s.x += v.x; s.y += v.y; s.z += v.z; s.w += v.w;
            q.x += v.x * v.x; q.y += v.y * v.y; q.z += v.z * v.z; q.w += v.w * v.w;
        }
        __shared__ float4 sS[256];
        __shared__ float4 sQ[256];
        sS[t] = s; sQ[t] = q;
        __syncthreads();
#pragma unroll
        for (int st = 128; st >= 32; st >>= 1) {
            if (t < st) {
                float4 a = sS[t + st], bb = sQ[t + st];
                sS[t].x += a.x; sS[t].y += a.y; sS[t].z += a.z; sS[t].w += a.w;
                sQ[t].x += bb.x; sQ[t].y += bb.y; sQ[t].z += bb.z; sQ[t].w += bb.w;
            }
            __syncthreads();
        }
        if (t < 32) {
            float4 a = sS[t], bb = sQ[t];
            atomicAdd(&sum[t * 4 + 0], a.x); atomicAdd(&sum[t * 4 + 1], a.y);
            atomicAdd(&sum[t * 4 + 2], a.z); atomicAdd(&sum[t * 4 + 3], a.w);
            atomicAdd(&sumsq[t * 4 + 0], bb.x); atomicAdd(&sumsq[t * 4 + 1], bb.y);
            atomicAdd(&sumsq[t * 4 + 2], bb.z); atomicAdd(&sumsq[t * 4 + 3], bb.w);
        }
        return;
    }
    if (b < BKB + SB + WB) {
        wprep_body(w1, wp1, (b - BKB - SB) * 256 + t, FIN, HC1);
        return;
    }
    wprep_body(w2, wp2, (b - BKB - SB - WB) * 256 + t, HC1, HC2);
}

// ---------------- per-tile CSR build (LDS sort) + finalize<128>(BN-in) as last block ----------------
__global__ __launch_bounds__(256) void k_csr(
    const int* __restrict__ gcur, const uint* __restrict__ buckets,
    ushort* __restrict__ csr, int* __restrict__ cnt, int* __restrict__ rowstart,
    const float* __restrict__ sum, const float* __restrict__ sumsq,
    const float* __restrict__ g, const float* __restrict__ be,
    float* __restrict__ scale, float* __restrict__ shift) {
    int t = threadIdx.x;
    if (blockIdx.x == NTILE) {
        if (t < 128) {
            float mean = sum[t] / (float)NN;
            float var = sumsq[t] / (float)NN - mean * mean;
            var = fmaxf(var, 0.f);
            float sc = g[t] * rsqrtf(var + EPSV);
            scale[t] = sc;
            shift[t] = be[t] - mean * sc;
        }
        return;
    }
    __shared__ uint ubuf[CAP];
    __shared__ int cnt256[256];
    __shared__ int scan[256];
    __shared__ int offs256[256];
    __shared__ int cur256[256];
    int tile = blockIdx.x;
    int t0 = tile << 8;
    // invariant: size <= FILLMAX -> sum of padded rows <= size + 256*15 <= CAP,
    // so ALL csr writes and gather reads stay inside this tile's region.
    int size = min(gcur[tile], FILLMAX);
    cnt256[t] = 0;
    __syncthreads();
    for (int i = t; i < size; i += 256) {
        uint u = buckets[(size_t)tile * CAP + i];
        ubuf[i] = u;
        atomicAdd(&cnt256[u & 255u], 1);
    }
    __syncthreads();
    int c = cnt256[t];
    int padded = (c + 15) & ~15;
    scan[t] = padded;
    __syncthreads();
#pragma unroll
    for (int off = 1; off < 256; off <<= 1) {
        int v = (t >= off) ? scan[t - off] : 0;
        __syncthreads();
        scan[t] += v;
        __syncthreads();
    }
    int excl = scan[t] - padded;
    offs256[t] = excl;
    cur256[t] = 0;
    int r = t0 + t;
    if (r < NN) {
        cnt[r] = c;
        rowstart[r] = tile * CAP + excl;
    }
    __syncthreads();
    for (int i = t; i < size; i += 256) {
        uint u = ubuf[i];
        int l = u & 255u;
        int p = atomicAdd(&cur256[l], 1);
        int w = offs256[l] + p;
        if (w < CAP) csr[(size_t)tile * CAP + w] = (ushort)(u >> 8);
    }
    if (r < NN) {
        for (int p = c; p < padded; ++p) {
            int w = excl + p;
            if (w < CAP) csr[(size_t)tile * CAP + w] = (ushort)NN;   // sentinel (zero row)
        }
    }
}

// ---------------- s0 = bf16( rsqrt(cnt+1) * BN_in(x) ) ----------------
__global__ void k_s0(const float* __restrict__ x, const int* __restrict__ cnt,
                     const float* __restrict__ scale, const float* __restrict__ shift,
                     ushort* __restrict__ s0) {
    int idx = blockIdx.x * blockDim.x + threadIdx.x;   // float4 index
    const int total = NN * FIN / 4;
    if (idx >= total) return;
    int row = idx >> 5;
    int c4 = idx & 31;
    float4 v = ((const float4*)x)[idx];
    float4 sc = ((const float4*)scale)[c4];
    float4 sh = ((const float4*)shift)[c4];
    float d = rsqrtf((float)(cnt[row] + 1));
    ushort4 o;
    o.x = f2bf((v.x * sc.x + sh.x) * d);
    o.y = f2bf((v.y * sc.y + sh.y) * d);
    o.z = f2bf((v.z * sc.z + sh.z) * d);
    o.w = f2bf((v.w * sc.w + sh.w) * d);
    ((ushort4*)s0)[idx] = o;
}

// ---------------- CSR gather: padded 16-deep, full-wave uint per row ----------------
__global__ __launch_bounds__(256) void k_gather(
    const int* __restrict__ cnt, const int* __restrict__ rowstart,
    const ushort* __restrict__ csr, const ushort* __restrict__ src,
    ushort* __restrict__ agg) {
    int wid = threadIdx.x >> 6;
    int lane = threadIdx.x & 63;
    int r = blockIdx.x * 4 + wid;
    if (r >= NN) return;
    int deg = cnt[r];
    int padded = (deg + 15) & ~15;
    int base = rowstart[r];
    const uint* sp = (const uint*)src;          // 64 uints (128 bf16) per row
    uint v = sp[(size_t)r * 64 + lane];         // self loop
    float a0 = ulo(v), a1 = uhi(v);
    for (int j = 0; j < padded; j += 16) {
        const ushort* p = csr + base + j;       // 16B-aligned (rows padded to 16)
        uint4 q0 = *(const uint4*)p;
        uint4 q1 = *(const uint4*)(p + 8);
        uint id[16];
        id[0]  = q0.x & 0xffffu; id[1]  = q0.x >> 16;
        id[2]  = q0.y & 0xffffu; id[3]  = q0.y >> 16;
        id[4]  = q0.z & 0xffffu; id[5]  = q0.z >> 16;
        id[6]  = q0.w & 0xffffu; id[7]  = q0.w >> 16;
        id[8]  = q1.x & 0xffffu; id[9]  = q1.x >> 16;
        id[10] = q1.y & 0xffffu; id[11] = q1.y >> 16;
        id[12] = q1.z & 0xffffu; id[13] = q1.z >> 16;
        id[14] = q1.w & 0xffffu; id[15] = q1.w >> 16;
#pragma unroll
        for (int k = 0; k < 16; ++k) id[k] = min(id[k], (uint)NN);  // defensive clamp to sentinel
        uint vv[16];
#pragma unroll
        for (int k = 0; k < 16; ++k) vv[k] = sp[(size_t)id[k] * 64 + lane];
#pragma unroll
        for (int k = 0; k < 16; ++k) { a0 += ulo(vv[k]); a1 += uhi(vv[k]); }
    }
    float d = rsqrtf((float)(deg + 1));
    uint o = ((uint)f2bf(a1 * d) << 16) | (uint)f2bf(a0 * d);
    ((uint*)agg)[(size_t)r * 64 + lane] = o;
}

// ---------------- MFMA GEMM 1 + fused BN1 col stats; y1 stored bf16 ----------------
__global__ __launch_bounds__(256) void k_mm1(
    const ushort* __restrict__ Abf,   // [NN][128] bf16
    const ushort* __restrict__ wp,    // w1 prepped
    const float* __restrict__ bias,   // b1 [256]
    ushort* __restrict__ Y,           // [NN][256] bf16
    float* __restrict__ sum, float* __restrict__ sumsq)
{
    const int K = 128, NC = 256, KS = K / 16, NT = NC / 32;
    int tid = threadIdx.x;
    int wid = tid >> 6;
    int lane = tid & 63;
    int rbase = blockIdx.x * 128 + wid * 32;
    int arow = rbase + (lane & 31);
    int khalf = lane >> 5;

    __shared__ float lsum[NC];
    __shared__ float lsq[NC];
    lsum[tid] = 0.f; lsq[tid] = 0.f;
    __syncthreads();

    f32x16 acc[NT];
#pragma unroll
    for (int t = 0; t < NT; ++t)
#pragma unroll
        for (int i = 0; i < 16; ++i) acc[t][i] = 0.f;

    const uint4* Bq = (const uint4*)wp;
    const uint4* Aq = (const uint4*)Abf;   // 16 uint4 per row
#pragma unroll
    for (int s = 0; s < KS; ++s) {
        BF8U au;
        if (arow < NN) au.q = Aq[(size_t)arow * (K / 8) + s * 2 + khalf];
        else au.q = make_uint4(0, 0, 0, 0);
#pragma unroll
        for (int t = 0; t < NT; ++t) {
            BF8U bu;
            bu.q = Bq[(t * KS + s) * 64 + lane];
            acc[t] = __builtin_amdgcn_mfma_f32_32x32x16_bf16(au.v, bu.v, acc[t], 0, 0, 0);
        }
    }

#pragma unroll
    for (int t = 0; t < NT; ++t) {
        int col = t * 32 + (lane & 31);
        float bv = bias[col];
        float fs = 0.f, fq = 0.f;
#pragma unroll
        for (int q = 0; q < 4; ++q) {
#pragma unroll
            for (int i = 0; i < 4; ++i) {
                int r = rbase + q * 8 + khalf * 4 + i;
                if (r < NN) {
                    float v = acc[t][q * 4 + i] + bv;
                    Y[(size_t)r * NC + col] = f2bf(v);
                    fs += v; fq += v * v;
                }
            }
        }
        atomicAdd(&lsum[col], fs);
        atomicAdd(&lsq[col], fq);
    }
    __syncthreads();
    atomicAdd(&sum[tid], lsum[tid]);
    atomicAdd(&sumsq[tid], lsq[tid]);
}

// ---------------- MFMA GEMM 2 (BN1 finalize folded into prologue) ----------------
__global__ __launch_bounds__(256) void k_mm2(
    const ushort* __restrict__ Y,     // [NN][256] bf16
    const ushort* __restrict__ wp,    // w2 prepped
    const float* __restrict__ sum1, const float* __restrict__ sq1,
    const float* __restrict__ g1, const float* __restrict__ be1,
    const int* __restrict__ cnt,
    ushort* __restrict__ S2)          // [NN][128] bf16
{
    const int K = 256, NC = 128, KS = K / 16, NT = NC / 32;
    __shared__ float ssc[K];
    __shared__ float ssh[K];
    {
        int c = threadIdx.x;   // 256 threads, 256 cols
        float mean = sum1[c] / (float)NN;
        float var = fmaxf(sq1[c] / (float)NN - mean * mean, 0.f);
        float s = g1[c] * rsqrtf(var + EPSV);
        ssc[c] = s;
        ssh[c] = be1[c] - mean * s;
    }
    __syncthreads();

    int wid = threadIdx.x >> 6;
    int lane = threadIdx.x & 63;
    int rbase = blockIdx.x * 128 + wid * 32;
    int arow = rbase + (lane & 31);
    int khalf = lane >> 5;

    f32x16 acc[NT];
#pragma unroll
    for (int t = 0; t < NT; ++t)
#pragma unroll
        for (int i = 0; i < 16; ++i) acc[t][i] = 0.f;

    const uint4* Bq = (const uint4*)wp;
#pragma unroll
    for (int s = 0; s < KS; ++s) {
        int k0 = s * 16 + khalf * 8;
        BF8U au;
        if (arow < NN) {
            uint4 y = *(const uint4*)&Y[(size_t)arow * K + k0];
            float4 c0 = *(const float4*)&ssc[k0];
            float4 c1 = *(const float4*)&ssc[k0 + 4];
            float4 h0 = *(const float4*)&ssh[k0];
            float4 h1 = *(const float4*)&ssh[k0 + 4];
            au.u[0] = f2bf(fmaxf(bf2f((ushort)(y.x & 0xffffu)) * c0.x + h0.x, 0.f));
            au.u[1] = f2bf(fmaxf(bf2f((ushort)(y.x >> 16))     * c0.y + h0.y, 0.f));
            au.u[2] = f2bf(fmaxf(bf2f((ushort)(y.y & 0xffffu)) * c0.z + h0.z, 0.f));
            au.u[3] = f2bf(fmaxf(bf2f((ushort)(y.y >> 16))     * c0.w + h0.w, 0.f));
            au.u[4] = f2bf(fmaxf(bf2f((ushort)(y.z & 0xffffu)) * c1.x + h1.x, 0.f));
            au.u[5] = f2bf(fmaxf(bf2f((ushort)(y.z >> 16))     * c1.y + h1.y, 0.f));
            au.u[6] = f2bf(fmaxf(bf2f((ushort)(y.w & 0xffffu)) * c1.z + h1.z, 0.f));
            au.u[7] = f2bf(fmaxf(bf2f((ushort)(y.w >> 16))     * c1.w + h1.w, 0.f));
        } else {
            au.q = make_uint4(0, 0, 0, 0);
        }
#pragma unroll
        for (int t = 0; t < NT; ++t) {
            BF8U bu;
            bu.q = Bq[(t * KS + s) * 64 + lane];
            acc[t] = __builtin_amdgcn_mfma_f32_32x32x16_bf16(au.v, bu.v, acc[t], 0, 0, 0);
        }
    }

#pragma unroll
    for (int q = 0; q < 4; ++q) {
#pragma unroll
        for (int i = 0; i < 4; ++i) {
            int r = rbase + q * 8 + khalf * 4 + i;
            if (r < NN) {
                float dv = rsqrtf((float)(cnt[r] + 1));
#pragma unroll
                for (int t = 0; t < NT; ++t) {
                    int col = t * 32 + (lane & 31);
                    S2[(size_t)r * NC + col] = f2bf(acc[t][q * 4 + i] * dv);
                }
            }
        }
    }
}

// ---------------- BN2 stats only (no store): v = agg2 + b2 ----------------
__global__ __launch_bounds__(256) void k_post2(const ushort* __restrict__ agg2,
                                               const float* __restrict__ b2,
                                               float* __restrict__ sum, float* __restrict__ sumsq) {
    const int F4 = 32, RIF = 8, RPB = 128;
    int t = threadIdx.x;
    int c4 = t & 31;
    int ro = t >> 5;
    int r0 = blockIdx.x * RPB;
    int r1 = min(r0 + RPB, NN);
    float4 bb = ((const float4*)b2)[c4];
    float4 s = make_float4(0.f, 0.f, 0.f, 0.f);
    float4 q = make_float4(0.f, 0.f, 0.f, 0.f);
    for (int r = r0 + ro; r < r1; r += RIF) {
        ushort4 u = ((const ushort4*)agg2)[(size_t)r * F4 + c4];
        float4 v;
        v.x = bf2f(u.x) + bb.x; v.y = bf2f(u.y) + bb.y;
        v.z = bf2f(u.z) + bb.z; v.w = bf2f(u.w) + bb.w;
        s.x += v.x; s.y += v.y; s.z += v.z; s.w += v.w;
        q.x += v.x * v.x; q.y += v.y * v.y; q.z += v.z * v.z; q.w += v.w * v.w;
    }
    __shared__ float4 sS[256];
    __shared__ float4 sQ[256];
    sS[t] = s; sQ[t] = q;
    __syncthreads();
#pragma unroll
    for (int st = 128; st >= F4; st >>= 1) {
        if (t < st) {
            float4 a = sS[t + st], b = sQ[t + st];
            sS[t].x += a.x; sS[t].y += a.y; sS[t].z += a.z; sS[t].w += a.w;
            sQ[t].x += b.x; sQ[t].y += b.y; sQ[t].z += b.z; sQ[t].w += b.w;
        }
        __syncthreads();
    }
    if (t < F4) {
        float4 a = sS[t], b = sQ[t];
        atomicAdd(&sum[t * 4 + 0], a.x); atomicAdd(&sum[t * 4 + 1], a.y);
        atomicAdd(&sum[t * 4 + 2], a.z); atomicAdd(&sum[t * 4 + 3], a.w);
        atomicAdd(&sumsq[t * 4 + 0], b.x); atomicAdd(&sumsq[t * 4 + 1], b.y);
        atomicAdd(&sumsq[t * 4 + 2], b.z); atomicAdd(&sumsq[t * 4 + 3], b.w);
    }
}

// ---------------- final: out = relu(sc2*(agg2+b2)+sh2), BN2 finalize folded ----------------
__global__ void k_bnrelu(const ushort* __restrict__ agg2, const float* __restrict__ b2,
                         const float* __restrict__ sum, const float* __restrict__ sumsq,
                         const float* __restrict__ g, const float* __restrict__ be,
                         float* __restrict__ out) {
    int idx = blockIdx.x * blockDim.x + threadIdx.x;
    const int total = NN * HC2 / 4;
    if (idx >= total) return;
    int c4 = idx & 31;
    float4 sm = ((const float4*)sum)[c4];
    float4 sq = ((const float4*)sumsq)[c4];
    float4 gg = ((const float4*)g)[c4];
    float4 bee = ((const float4*)be)[c4];
    float4 bb = ((const float4*)b2)[c4];
    float4 mean, sc, sh;
    mean.x = sm.x / (float)NN; mean.y = sm.y / (float)NN;
    mean.z = sm.z / (float)NN; mean.w = sm.w / (float)NN;
    sc.x = gg.x * rsqrtf(fmaxf(sq.x / (float)NN - mean.x * mean.x, 0.f) + EPSV);
    sc.y = gg.y * rsqrtf(fmaxf(sq.y / (float)NN - mean.y * mean.y, 0.f) + EPSV);
    sc.z = gg.z * rsqrtf(fmaxf(sq.z / (float)NN - mean.z * mean.z, 0.f) + EPSV);
    sc.w = gg.w * rsqrtf(fmaxf(sq.w / (float)NN - mean.w * mean.w, 0.f) + EPSV);
    sh.x = bee.x - mean.x * sc.x; sh.y = bee.y - mean.y * sc.y;
    sh.z = bee.z - mean.z * sc.z; sh.w = bee.w - mean.w * sc.w;
    ushort4 u = ((const ushort4*)agg2)[idx];
    float4 v;
    v.x = fmaxf((bf2f(u.x) + bb.x) * sc.x + sh.x, 0.f);
    v.y = fmaxf((bf2f(u.y) + bb.y) * sc.y + sh.y, 0.f);
    v.z = fmaxf((bf2f(u.z) + bb.z) * sc.z + sh.z, 0.f);
    v.w = fmaxf((bf2f(u.w) + bb.w) * sc.w + sh.w, 0.f);
    ((float4*)out)[idx] = v;
}

extern "C" void kernel_launch(void* const* d_in, const int* in_sizes, int n_in,
                              void* d_out, int out_size, void* d_ws, size_t ws_size,
                              hipStream_t stream) {
    const float* x     = (const float*)d_in[0];
    const int*   ei    = (const int*)d_in[1];
    const float* g_in  = (const float*)d_in[2];
    const float* be_in = (const float*)d_in[3];
    const float* w1    = (const float*)d_in[4];
    const float* b1    = (const float*)d_in[5];
    const float* g1    = (const float*)d_in[6];
    const float* be1   = (const float*)d_in[7];
    const float* w2    = (const float*)d_in[8];
    const float* b2    = (const float*)d_in[9];
    const float* g2    = (const float*)d_in[10];
    const float* be2   = (const float*)d_in[11];
    float* out = (float*)d_out;

    // ---- workspace layout, in FLOAT units (4 B), verified non-overlapping ----
    float* ws = (float*)d_ws;
    float* stats = ws;                         // [0, 1024)
    float* sumIn = stats;        float* sqIn = stats + 128;
    float* sum1  = stats + 256;  float* sq1  = stats + 512;
    float* sum2  = stats + 768;  float* sq2  = stats + 896;
    float* params = ws + 1024;                 // [1024, 2048)
    float* scIn = params;        float* shIn = params + 128;
    ushort* wp1   = (ushort*)(ws + 2048);      // 32768 bf16 = 16384 f -> [2048, 18432)
    ushort* wp2   = (ushort*)(ws + 18432);     // [18432, 34816)
    ushort* y1u   = (ushort*)(ws + 34816);     // NN*256 bf16 = 6400000 f -> [34816, 6434816)
    ushort* s0bf  = (ushort*)(ws + 6434816);   // (NN+1)*128 bf16 = 3200064 f -> [6434816, 9634880)
    ushort* aggbf = (ushort*)(ws + 9634880);   // NN*128 bf16 = 3200000 f -> [9634880, 12834880)
    int* cnt      = (int*)(ws + 12834880);     // NN -> [12834880, 12884880)
    int* rowstart = (int*)(ws + 12884880);     // NN -> [12884880, 12934880)
    int* gcur     = (int*)(ws + 12934880);     // 256 -> [12934880, 12935136)
    uint* buckets = (uint*)(ws + 12935136);    // NTILE*CAP = 1655808 -> [12935136, 14590944)
    ushort* csr   = (ushort*)(ws + 14590944);  // NTILE*CAP us = 827904 f -> [14590944, 15418848)

    const int sblocks = (NN + 127) / 128;  // 391

    hipLaunchKernelGGL(k_init, dim3(4), dim3(256), 0, stream,
                       gcur, stats, (uint*)s0bf + (size_t)NN * 64);

    // bucket-fill || colstats(x) || wprep(w1) || wprep(w2)
    hipLaunchKernelGGL(k_bucket, dim3(BKB + SB + 2 * WB), dim3(256), 0, stream,
                       ei, gcur, buckets, x, sumIn, sqIn, w1, wp1, w2, wp2);

    // per-tile CSR sort + finalize(BN-in)
    hipLaunchKernelGGL(k_csr, dim3(NTILE + 1), dim3(256), 0, stream,
                       gcur, buckets, csr, cnt, rowstart,
                       sumIn, sqIn, g_in, be_in, scIn, shIn);

    hipLaunchKernelGGL(k_s0, dim3((NN * 32 + 255) / 256), dim3(256), 0, stream,
                       x, cnt, scIn, shIn, s0bf);

    hipLaunchKernelGGL(k_gather, dim3((NN + 3) / 4), dim3(256), 0, stream,
                       cnt, rowstart, csr, s0bf, aggbf);

    hipLaunchKernelGGL(k_mm1, dim3(sblocks), dim3(256), 0, stream, aggbf, wp1, b1, y1u, sum1, sq1);

    hipLaunchKernelGGL(k_mm2, dim3(sblocks), dim3(256), 0, stream,
                       y1u, wp2, sum1, sq1, g1, be1, cnt, s0bf);
    hipLaunchKernelGGL(k_gather, dim3((NN + 3) / 4), dim3(256), 0, stream,
                       cnt, rowstart, csr, s0bf, aggbf);

    hipLaunchKernelGGL(k_post2, dim3(sblocks), dim3(256), 0, stream, aggbf, b2, sum2, sq2);
    hipLaunchKernelGGL(k_bnrelu, dim3((NN * 32 + 255) / 256), dim3(256), 0, stream,
                       aggbf, b2, sum2, sq2, g2, be2, out);
}

// Round 12
// 229.169 us; speedup vs baseline: 1.1158x; 1.1158x over previous
//
#include <hip/hip_runtime.h>
#include <hip/hip_bf16.h>

#define NN 50000
#define NE 800000
#define FIN 128
#define HC1 256
#define HC2 128
#define EPSV 1e-5f
#define NTILE 196     // ceil(NN/256)
#define CAP 8448      // per-tile bucket/CSR capacity
#define FILLMAX (CAP - 3840)  // 4608: scan total <= CAP always
#define NQ 12500      // NN/4 row-quads

typedef __attribute__((ext_vector_type(8))) short bf8;     // 8 bf16 (4 VGPRs) MFMA operand
typedef __attribute__((ext_vector_type(16))) float f32x16; // 32x32 MFMA accumulator

union BF8U { bf8 v; ushort u[8]; uint4 q; };

__device__ __forceinline__ float bf2f(ushort u) {
    union { uint i; float f; } c; c.i = ((uint)u) << 16; return c.f;
}
__device__ __forceinline__ float ulo(uint u) {
    union { uint i; float f; } c; c.i = u << 16; return c.f;
}
__device__ __forceinline__ float uhi(uint u) {
    union { uint i; float f; } c; c.i = u & 0xffff0000u; return c.f;
}
__device__ __forceinline__ ushort f2bf(float f) {
    return __builtin_bit_cast(ushort, __float2bfloat16(f));  // RNE
}

// ---------------- init: zero bucket cursors + stats + sentinel row ----------------
__global__ void k_init(int* __restrict__ gcur, float* __restrict__ stats, uint* __restrict__ s0row) {
    int i = blockIdx.x * blockDim.x + threadIdx.x;
    if (i < 256) gcur[i] = 0;
    if (i < 1024) stats[i] = 0.0f;
    if (i < 64) s0row[i] = 0u;   // zero sentinel row (index NN) of s0 buffer
}

// ---------------- merged: bucket-fill || colstats<128>(x) || wprep(w1) || wprep(w2) ----------------
#define BKB NTILE   // fill blocks (4096 edges each) — r10 config, claims minimized
#define SB 391      // colstats blocks
#define WB 128      // wprep blocks each

__device__ __forceinline__ void wprep_body(const float* __restrict__ W, ushort* __restrict__ wp,
                                           int idx, int K, int NC) {
    int j = idx & 7;
    int lane = (idx >> 3) & 63;
    int ts = idx >> 9;
    int KS = K / 16;
    int s = ts % KS;
    int t = ts / KS;
    int n = t * 32 + (lane & 31);
    int k = s * 16 + (lane >> 5) * 8 + j;
    wp[idx] = f2bf(W[(size_t)k * NC + n]);
}

__global__ __launch_bounds__(256) void k_bucket(
    const int* __restrict__ ei, int* __restrict__ gcur, uint* __restrict__ buckets,
    const float* __restrict__ x, float* __restrict__ sum, float* __restrict__ sumsq,
    const float* __restrict__ w1, ushort* __restrict__ wp1,
    const float* __restrict__ w2, ushort* __restrict__ wp2) {
    int b = blockIdx.x;
    int t = threadIdx.x;
    if (b < BKB) {
        __shared__ int hist[NTILE];
        __shared__ int base[NTILE];
        if (t < NTILE) hist[t] = 0;
        __syncthreads();
        int e0 = b * 4096;
        int es[16], ed[16];
#pragma unroll
        for (int i = 0; i < 16; ++i) {
            int e = e0 + i * 256 + t;
            if (e < NE) {
                int s = ei[e];
                int d = ei[NE + e];
                s = min(max(s, 0), NN - 1);
                d = min(max(d, 0), NN - 1);
                es[i] = s; ed[i] = d;
                atomicAdd(&hist[d >> 8], 1);
            } else es[i] = -1;
        }
        __syncthreads();
        if (t < NTILE) base[t] = atomicAdd(&gcur[t], hist[t]);
        __syncthreads();
        if (t < NTILE) hist[t] = 0;   // reuse as local cursor
        __syncthreads();
#pragma unroll
        for (int i = 0; i < 16; ++i) {
            if (es[i] >= 0) {
                int tile = ed[i] >> 8;
                int lofs = atomicAdd(&hist[tile], 1);
                int pos = base[tile] + lofs;
                if (pos < CAP) buckets[(size_t)tile * CAP + pos] = ((uint)es[i] << 8) | (uint)(ed[i] & 255);
            }
        }
        return;
    }
    if (b < BKB + SB) {
        const int F4 = 32, RIF = 8, RPB = 128;
        int c4 = t & 31;
        int ro = t >> 5;
        int r0 = (b - BKB) * RPB;
        int r1 = min(r0 + RPB, NN);
        float4 s = make_float4(0.f, 0.f, 0.f, 0.f);
        float4 q = make_float4(0.f, 0.f, 0.f, 0.f);
        for (int r = r0 + ro; r < r1; r += RIF) {
            float4 v = ((const float4*)x)[(size_t)r * F4 + c4];
            s.x += v.x; s.y += v.y; s.z += v.z; s.w += v.w;
            q.x += v.x * v.x; q.y += v.y * v.y; q.z += v.z * v.z; q.w += v.w * v.w;
        }
        __shared__ float4 sS[256];
        __shared__ float4 sQ[256];
        sS[t] = s; sQ[t] = q;
        __syncthreads();
#pragma unroll
        for (int st = 128; st >= 32; st >>= 1) {
            if (t < st) {
                float4 a = sS[t + st], bb = sQ[t + st];
                sS[t].x += a.x; sS[t].y += a.y; sS[t].z += a.z; sS[t].w += a.w;
                sQ[t].x += bb.x; sQ[t].y += bb.y; sQ[t].z += bb.z; sQ[t].w += bb.w;
            }
            __syncthreads();
        }
        if (t < 32) {
            float4 a = sS[t], bb = sQ[t];
            atomicAdd(&sum[t * 4 + 0], a.x); atomicAdd(&sum[t * 4 + 1], a.y);
            atomicAdd(&sum[t * 4 + 2], a.z); atomicAdd(&sum[t * 4 + 3], a.w);
            atomicAdd(&sumsq[t * 4 + 0], bb.x); atomicAdd(&sumsq[t * 4 + 1], bb.y);
            atomicAdd(&sumsq[t * 4 + 2], bb.z); atomicAdd(&sumsq[t * 4 + 3], bb.w);
        }
        return;
    }
    if (b < BKB + SB + WB) {
        wprep_body(w1, wp1, (b - BKB - SB) * 256 + t, FIN, HC1);
        return;
    }
    wprep_body(w2, wp2, (b - BKB - SB - WB) * 256 + t, HC1, HC2);
}

// ---- per-tile CSR build (LDS sort) + per-block BN-in finalize + s0 for tile rows ----
__global__ __launch_bounds__(256) void k_csr(
    const int* __restrict__ gcur, const uint* __restrict__ buckets,
    ushort* __restrict__ csr, int* __restrict__ cnt, int* __restrict__ rowstart,
    const float* __restrict__ sumIn, const float* __restrict__ sqIn,
    const float* __restrict__ g, const float* __restrict__ be,
    const float* __restrict__ x, ushort* __restrict__ s0) {
    __shared__ uint ubuf[CAP];
    __shared__ int cnt256[256];
    __shared__ int scan[256];
    __shared__ int offs256[256];
    __shared__ int cur256[256];
    __shared__ int dcnt[256];
    __shared__ float ssc[128];
    __shared__ float ssh[128];
    int t = threadIdx.x;
    int tile = blockIdx.x;
    int t0 = tile << 8;
    // per-block BN-in finalize (redundant across blocks, cheap)
    if (t < 128) {
        float mean = sumIn[t] / (float)NN;
        float var = fmaxf(sqIn[t] / (float)NN - mean * mean, 0.f);
        float s = g[t] * rsqrtf(var + EPSV);
        ssc[t] = s;
        ssh[t] = be[t] - mean * s;
    }
    // invariant: size <= FILLMAX -> sum of padded rows <= size + 256*15 <= CAP
    int size = min(gcur[tile], FILLMAX);
    cnt256[t] = 0;
    __syncthreads();
    for (int i = t; i < size; i += 256) {
        uint u = buckets[(size_t)tile * CAP + i];
        ubuf[i] = u;
        atomicAdd(&cnt256[u & 255u], 1);
    }
    __syncthreads();
    int c = cnt256[t];
    dcnt[t] = c;
    int padded = (c + 15) & ~15;
    scan[t] = padded;
    __syncthreads();
#pragma unroll
    for (int off = 1; off < 256; off <<= 1) {
        int v = (t >= off) ? scan[t - off] : 0;
        __syncthreads();
        scan[t] += v;
        __syncthreads();
    }
    int excl = scan[t] - padded;
    offs256[t] = excl;
    cur256[t] = 0;
    int r = t0 + t;
    if (r < NN) {
        cnt[r] = c;
        rowstart[r] = tile * CAP + excl;
    }
    __syncthreads();
    for (int i = t; i < size; i += 256) {
        uint u = ubuf[i];
        int l = u & 255u;
        int p = atomicAdd(&cur256[l], 1);
        int w = offs256[l] + p;
        if (w < CAP) csr[(size_t)tile * CAP + w] = (ushort)(u >> 8);
    }
    if (r < NN) {
        for (int p = c; p < padded; ++p) {
            int w = excl + p;
            if (w < CAP) csr[(size_t)tile * CAP + w] = (ushort)NN;   // sentinel (zero row)
        }
    }
    // s0 for this tile's rows: s0[r] = bf16(dinv[r] * BN_in(x[r]))
    {
        int c4 = t & 31;          // float4 column
        float4 sc = *(const float4*)&ssc[c4 * 4];
        float4 sh = *(const float4*)&ssh[c4 * 4];
        for (int rr = t >> 5; rr < 256; rr += 8) {
            int row = t0 + rr;
            if (row >= NN) break;
            float d = rsqrtf((float)(dcnt[rr] + 1));
            float4 v = ((const float4*)x)[(size_t)row * 32 + c4];
            ushort4 o;
            o.x = f2bf((v.x * sc.x + sh.x) * d);
            o.y = f2bf((v.y * sc.y + sh.y) * d);
            o.z = f2bf((v.z * sc.z + sh.z) * d);
            o.w = f2bf((v.w * sc.w + sh.w) * d);
            ((ushort4*)s0)[(size_t)row * 32 + c4] = o;
        }
    }
}

// ---------------- CSR gather (grid-strided): agg[r] = dinv*(self + sum nbr) ----------------
// STATS: accumulate BN2 column stats of (agg_f32 + b2) into sum/sumsq
template<int STATS>
__global__ __launch_bounds__(256) void k_gather(
    const int* __restrict__ cnt, const int* __restrict__ rowstart,
    const ushort* __restrict__ csr, const ushort* __restrict__ src,
    ushort* __restrict__ agg, const float* __restrict__ b2,
    float* __restrict__ sum, float* __restrict__ sumsq) {
    __shared__ float lsum[128];
    __shared__ float lsq[128];
    int tid = threadIdx.x;
    int wid = tid >> 6;
    int lane = tid & 63;
    float bb0 = 0.f, bb1 = 0.f, fs0 = 0.f, fq0 = 0.f, fs1 = 0.f, fq1 = 0.f;
    if (STATS) {
        if (tid < 128) { lsum[tid] = 0.f; lsq[tid] = 0.f; }
        bb0 = b2[2 * lane];
        bb1 = b2[2 * lane + 1];
        __syncthreads();
    }
    const uint* sp = (const uint*)src;          // 64 uints (128 bf16) per row
    for (int q = blockIdx.x; q < NQ; q += gridDim.x) {
        int r = q * 4 + wid;
        int deg = cnt[r];
        int padded = (deg + 15) & ~15;
        int base = rowstart[r];
        uint v = sp[(size_t)r * 64 + lane];     // self loop
        float a0 = ulo(v), a1 = uhi(v);
        for (int j = 0; j < padded; j += 16) {
            const ushort* p = csr + base + j;   // 16B-aligned (rows padded to 16)
            uint4 q0 = *(const uint4*)p;
            uint4 q1 = *(const uint4*)(p + 8);
            uint id[16];
            id[0]  = q0.x & 0xffffu; id[1]  = q0.x >> 16;
            id[2]  = q0.y & 0xffffu; id[3]  = q0.y >> 16;
            id[4]  = q0.z & 0xffffu; id[5]  = q0.z >> 16;
            id[6]  = q0.w & 0xffffu; id[7]  = q0.w >> 16;
            id[8]  = q1.x & 0xffffu; id[9]  = q1.x >> 16;
            id[10] = q1.y & 0xffffu; id[11] = q1.y >> 16;
            id[12] = q1.z & 0xffffu; id[13] = q1.z >> 16;
            id[14] = q1.w & 0xffffu; id[15] = q1.w >> 16;
#pragma unroll
            for (int k = 0; k < 16; ++k) id[k] = min(id[k], (uint)NN);  // clamp to sentinel
            uint vv[16];
#pragma unroll
            for (int k = 0; k < 16; ++k) vv[k] = sp[(size_t)id[k] * 64 + lane];
#pragma unroll
            for (int k = 0; k < 16; ++k) { a0 += ulo(vv[k]); a1 += uhi(vv[k]); }
        }
        float d = rsqrtf((float)(deg + 1));
        float a0f = a0 * d, a1f = a1 * d;
        if (STATS) {
            float v0 = a0f + bb0, v1 = a1f + bb1;
            fs0 += v0; fq0 += v0 * v0;
            fs1 += v1; fq1 += v1 * v1;
        }
        uint o = ((uint)f2bf(a1f) << 16) | (uint)f2bf(a0f);
        ((uint*)agg)[(size_t)r * 64 + lane] = o;
    }
    if (STATS) {
        atomicAdd(&lsum[2 * lane], fs0);
        atomicAdd(&lsum[2 * lane + 1], fs1);
        atomicAdd(&lsq[2 * lane], fq0);
        atomicAdd(&lsq[2 * lane + 1], fq1);
        __syncthreads();
        if (tid < 128) {
            atomicAdd(&sum[tid], lsum[tid]);
            atomicAdd(&sumsq[tid], lsq[tid]);
        }
    }
}

// ---------------- MFMA GEMM 1 + fused BN1 col stats; y1 stored bf16 ----------------
__global__ __launch_bounds__(256) void k_mm1(
    const ushort* __restrict__ Abf,   // [NN][128] bf16
    const ushort* __restrict__ wp,    // w1 prepped
    const float* __restrict__ bias,   // b1 [256]
    ushort* __restrict__ Y,           // [NN][256] bf16
    float* __restrict__ sum, float* __restrict__ sumsq)
{
    const int K = 128, NC = 256, KS = K / 16, NT = NC / 32;
    int tid = threadIdx.x;
    int wid = tid >> 6;
    int lane = tid & 63;
    int rbase = blockIdx.x * 128 + wid * 32;
    int arow = rbase + (lane & 31);
    int khalf = lane >> 5;

    __shared__ float lsum[NC];
    __shared__ float lsq[NC];
    lsum[tid] = 0.f; lsq[tid] = 0.f;
    __syncthreads();

    f32x16 acc[NT];
#pragma unroll
    for (int t = 0; t < NT; ++t)
#pragma unroll
        for (int i = 0; i < 16; ++i) acc[t][i] = 0.f;

    const uint4* Bq = (const uint4*)wp;
    const uint4* Aq = (const uint4*)Abf;   // 16 uint4 per row
#pragma unroll
    for (int s = 0; s < KS; ++s) {
        BF8U au;
        if (arow < NN) au.q = Aq[(size_t)arow * (K / 8) + s * 2 + khalf];
        else au.q = make_uint4(0, 0, 0, 0);
#pragma unroll
        for (int t = 0; t < NT; ++t) {
            BF8U bu;
            bu.q = Bq[(t * KS + s) * 64 + lane];
            acc[t] = __builtin_amdgcn_mfma_f32_32x32x16_bf16(au.v, bu.v, acc[t], 0, 0, 0);
        }
    }

#pragma unroll
    for (int t = 0; t < NT; ++t) {
        int col = t * 32 + (lane & 31);
        float bv = bias[col];
        float fs = 0.f, fq = 0.f;
#pragma unroll
        for (int q = 0; q < 4; ++q) {
#pragma unroll
            for (int i = 0; i < 4; ++i) {
                int r = rbase + q * 8 + khalf * 4 + i;
                if (r < NN) {
                    float v = acc[t][q * 4 + i] + bv;
                    Y[(size_t)r * NC + col] = f2bf(v);
                    fs += v; fq += v * v;
                }
            }
        }
        atomicAdd(&lsum[col], fs);
        atomicAdd(&lsq[col], fq);
    }
    __syncthreads();
    atomicAdd(&sum[tid], lsum[tid]);
    atomicAdd(&sumsq[tid], lsq[tid]);
}

// ---------------- MFMA GEMM 2 (BN1 finalize folded into prologue) ----------------
__global__ __launch_bounds__(256) void k_mm2(
    const ushort* __restrict__ Y,     // [NN][256] bf16
    const ushort* __restrict__ wp,    // w2 prepped
    const float* __restrict__ sum1, const float* __restrict__ sq1,
    const float* __restrict__ g1, const float* __restrict__ be1,
    const int* __restrict__ cnt,
    ushort* __restrict__ S2)          // [NN][128] bf16
{
    const int K = 256, NC = 128, KS = K / 16, NT = NC / 32;
    __shared__ float ssc[K];
    __shared__ float ssh[K];
    {
        int c = threadIdx.x;   // 256 threads, 256 cols
        float mean = sum1[c] / (float)NN;
        float var = fmaxf(sq1[c] / (float)NN - mean * mean, 0.f);
        float s = g1[c] * rsqrtf(var + EPSV);
        ssc[c] = s;
        ssh[c] = be1[c] - mean * s;
    }
    __syncthreads();

    int wid = threadIdx.x >> 6;
    int lane = threadIdx.x & 63;
    int rbase = blockIdx.x * 128 + wid * 32;
    int arow = rbase + (lane & 31);
    int khalf = lane >> 5;

    f32x16 acc[NT];
#pragma unroll
    for (int t = 0; t < NT; ++t)
#pragma unroll
        for (int i = 0; i < 16; ++i) acc[t][i] = 0.f;

    const uint4* Bq = (const uint4*)wp;
#pragma unroll
    for (int s = 0; s < KS; ++s) {
        int k0 = s * 16 + khalf * 8;
        BF8U au;
        if (arow < NN) {
            uint4 y = *(const uint4*)&Y[(size_t)arow * K + k0];
            float4 c0 = *(const float4*)&ssc[k0];
            float4 c1 = *(const float4*)&ssc[k0 + 4];
            float4 h0 = *(const float4*)&ssh[k0];
            float4 h1 = *(const float4*)&ssh[k0 + 4];
            au.u[0] = f2bf(fmaxf(bf2f((ushort)(y.x & 0xffffu)) * c0.x + h0.x, 0.f));
            au.u[1] = f2bf(fmaxf(bf2f((ushort)(y.x >> 16))     * c0.y + h0.y, 0.f));
            au.u[2] = f2bf(fmaxf(bf2f((ushort)(y.y & 0xffffu)) * c0.z + h0.z, 0.f));
            au.u[3] = f2bf(fmaxf(bf2f((ushort)(y.y >> 16))     * c0.w + h0.w, 0.f));
            au.u[4] = f2bf(fmaxf(bf2f((ushort)(y.z & 0xffffu)) * c1.x + h1.x, 0.f));
            au.u[5] = f2bf(fmaxf(bf2f((ushort)(y.z >> 16))     * c1.y + h1.y, 0.f));
            au.u[6] = f2bf(fmaxf(bf2f((ushort)(y.w & 0xffffu)) * c1.z + h1.z, 0.f));
            au.u[7] = f2bf(fmaxf(bf2f((ushort)(y.w >> 16))     * c1.w + h1.w, 0.f));
        } else {
            au.q = make_uint4(0, 0, 0, 0);
        }
#pragma unroll
        for (int t = 0; t < NT; ++t) {
            BF8U bu;
            bu.q = Bq[(t * KS + s) * 64 + lane];
            acc[t] = __builtin_amdgcn_mfma_f32_32x32x16_bf16(au.v, bu.v, acc[t], 0, 0, 0);
        }
    }

#pragma unroll
    for (int q = 0; q < 4; ++q) {
#pragma unroll
        for (int i = 0; i < 4; ++i) {
            int r = rbase + q * 8 + khalf * 4 + i;
            if (r < NN) {
                float dv = rsqrtf((float)(cnt[r] + 1));
#pragma unroll
                for (int t = 0; t < NT; ++t) {
                    int col = t * 32 + (lane & 31);
                    S2[(size_t)r * NC + col] = f2bf(acc[t][q * 4 + i] * dv);
                }
            }
        }
    }
}

// ---------------- final: out = relu(sc2*(agg2+b2)+sh2), BN2 finalize folded ----------------
__global__ void k_bnrelu(const ushort* __restrict__ agg2, const float* __restrict__ b2,
                         const float* __restrict__ sum, const float* __restrict__ sumsq,
                         const float* __restrict__ g, const float* __restrict__ be,
                         float* __restrict__ out) {
    int idx = blockIdx.x * blockDim.x + threadIdx.x;
    const int total = NN * HC2 / 4;
    if (idx >= total) return;
    int c4 = idx & 31;
    float4 sm = ((const float4*)sum)[c4];
    float4 sq = ((const float4*)sumsq)[c4];
    float4 gg = ((const float4*)g)[c4];
    float4 bee = ((const float4*)be)[c4];
    float4 bb = ((const float4*)b2)[c4];
    float4 mean, sc, sh;
    mean.x = sm.x / (float)NN; mean.y = sm.y / (float)NN;
    mean.z = sm.z / (float)NN; mean.w = sm.w / (float)NN;
    sc.x = gg.x * rsqrtf(fmaxf(sq.x / (float)NN - mean.x * mean.x, 0.f) + EPSV);
    sc.y = gg.y * rsqrtf(fmaxf(sq.y / (float)NN - mean.y * mean.y, 0.f) + EPSV);
    sc.z = gg.z * rsqrtf(fmaxf(sq.z / (float)NN - mean.z * mean.z, 0.f) + EPSV);
    sc.w = gg.w * rsqrtf(fmaxf(sq.w / (float)NN - mean.w * mean.w, 0.f) + EPSV);
    sh.x = bee.x - mean.x * sc.x; sh.y = bee.y - mean.y * sc.y;
    sh.z = bee.z - mean.z * sc.z; sh.w = bee.w - mean.w * sc.w;
    ushort4 u = ((const ushort4*)agg2)[idx];
    float4 v;
    v.x = fmaxf((bf2f(u.x) + bb.x) * sc.x + sh.x, 0.f);
    v.y = fmaxf((bf2f(u.y) + bb.y) * sc.y + sh.y, 0.f);
    v.z = fmaxf((bf2f(u.z) + bb.z) * sc.z + sh.z, 0.f);
    v.w = fmaxf((bf2f(u.w) + bb.w) * sc.w + sh.w, 0.f);
    ((float4*)out)[idx] = v;
}

extern "C" void kernel_launch(void* const* d_in, const int* in_sizes, int n_in,
                              void* d_out, int out_size, void* d_ws, size_t ws_size,
                              hipStream_t stream) {
    const float* x     = (const float*)d_in[0];
    const int*   ei    = (const int*)d_in[1];
    const float* g_in  = (const float*)d_in[2];
    const float* be_in = (const float*)d_in[3];
    const float* w1    = (const float*)d_in[4];
    const float* b1    = (const float*)d_in[5];
    const float* g1    = (const float*)d_in[6];
    const float* be1   = (const float*)d_in[7];
    const float* w2    = (const float*)d_in[8];
    const float* b2    = (const float*)d_in[9];
    const float* g2    = (const float*)d_in[10];
    const float* be2   = (const float*)d_in[11];
    float* out = (float*)d_out;

    // ---- workspace layout, in FLOAT units (4 B), non-overlapping ----
    float* ws = (float*)d_ws;
    float* stats = ws;                         // [0, 1024)
    float* sumIn = stats;        float* sqIn = stats + 128;
    float* sum1  = stats + 256;  float* sq1  = stats + 512;
    float* sum2  = stats + 768;  float* sq2  = stats + 896;
    ushort* wp1   = (ushort*)(ws + 2048);      // [2048, 18432)
    ushort* wp2   = (ushort*)(ws + 18432);     // [18432, 34816)
    ushort* y1u   = (ushort*)(ws + 34816);     // NN*256 bf16 -> [34816, 6434816)
    ushort* s0bf  = (ushort*)(ws + 6434816);   // (NN+1)*128 bf16 -> [6434816, 9634880)
    ushort* aggbf = (ushort*)(ws + 9634880);   // NN*128 bf16 -> [9634880, 12834880)
    int* cnt      = (int*)(ws + 12834880);     // [12834880, 12884880)
    int* rowstart = (int*)(ws + 12884880);     // [12884880, 12934880)
    int* gcur     = (int*)(ws + 12934880);     // [12934880, 12935136)
    uint* buckets = (uint*)(ws + 12935136);    // [12935136, 14590944)
    ushort* csr   = (ushort*)(ws + 14590944);  // [14590944, 15418848)

    const int sblocks = (NN + 127) / 128;  // 391

    hipLaunchKernelGGL(k_init, dim3(4), dim3(256), 0, stream,
                       gcur, stats, (uint*)s0bf + (size_t)NN * 64);

    // bucket-fill || colstats(x) || wprep(w1) || wprep(w2)
    hipLaunchKernelGGL(k_bucket, dim3(BKB + SB + 2 * WB), dim3(256), 0, stream,
                       ei, gcur, buckets, x, sumIn, sqIn, w1, wp1, w2, wp2);

    // per-tile CSR build + BN-in finalize + s0
    hipLaunchKernelGGL(k_csr, dim3(NTILE), dim3(256), 0, stream,
                       gcur, buckets, csr, cnt, rowstart,
                       sumIn, sqIn, g_in, be_in, x, s0bf);

    hipLaunchKernelGGL(k_gather<0>, dim3(NQ), dim3(256), 0, stream,
                       cnt, rowstart, csr, s0bf, aggbf, nullptr, nullptr, nullptr);

    hipLaunchKernelGGL(k_mm1, dim3(sblocks), dim3(256), 0, stream, aggbf, wp1, b1, y1u, sum1, sq1);

    hipLaunchKernelGGL(k_mm2, dim3(sblocks), dim3(256), 0, stream,
                       y1u, wp2, sum1, sq1, g1, be1, cnt, s0bf);

    // gather2 + fused BN2 stats (grid-strided)
    hipLaunchKernelGGL(k_gather<1>, dim3(784), dim3(256), 0, stream,
                       cnt, rowstart, csr, s0bf, aggbf, b2, sum2, sq2);

    hipLaunchKernelGGL(k_bnrelu, dim3((NN * 32 + 255) / 256), dim3(256), 0, stream,
                       aggbf, b2, sum2, sq2, g2, be2, out);
}